// Round 5
// baseline (605.754 us; speedup 1.0000x reference)
//
#include <hip/hip_runtime.h>

#define N_ROWS 65536
#define DIM    512
#define K_CENT 4096
#define TILE_M 256               // rows per block = 4 waves x 64 private rows
#define TILE_N 64                // centers per tile
#define NCT    (K_CENT / TILE_N) // 64 tiles
#define KSTEPS 8                 // DIM / 64
#define THREADS 256
#define WCAP   1024              // per-wave candidate pool entries (64*16)
#define WTRIG  512               // headroom 512 above trigger (= verified R2 margin)
#define MARGIN 22.0f
#define SCALE1 0x7F7F7F7F        // e8m0 scale = 2^0 in every byte

typedef float  floatx4  __attribute__((ext_vector_type(4)));
typedef float  floatx16 __attribute__((ext_vector_type(16)));
typedef int    intx4    __attribute__((ext_vector_type(4)));
typedef int    intx8    __attribute__((ext_vector_type(8)));

// order-preserving float<->uint map
__device__ __forceinline__ unsigned mapF(float f) {
  unsigned u = __float_as_uint(f);
  return (u & 0x80000000u) ? ~u : (u | 0x80000000u);
}
__device__ __forceinline__ float unmapF(unsigned m) {
  unsigned u = (m & 0x80000000u) ? (m ^ 0x80000000u) : ~m;
  return __uint_as_float(u);
}

__device__ __forceinline__ void gload_lds16(const void* g, void* l) {
  __builtin_amdgcn_global_load_lds(
      (const __attribute__((address_space(1))) void*)g,
      (__attribute__((address_space(3))) void*)l, 16, 0, 0);
}

// pack 4 floats -> 4 OCP e4m3 bytes
__device__ __forceinline__ int pk4(float a, float b, float c, float d) {
  int r = __builtin_amdgcn_cvt_pk_fp8_f32(a, b, 0, false);
  r = __builtin_amdgcn_cvt_pk_fp8_f32(c, d, r, true);
  return r;
}

// intra-wave LDS ordering fence (no barrier): drain lgkm, pin schedule
#define WAVE_LDS_FENCE() do { asm volatile("s_waitcnt lgkmcnt(0)" ::: "memory"); \
                              __builtin_amdgcn_sched_barrier(0); } while (0)

// Centers only: fp32 -> fp8 (16 elems/thread) + EXACT fp32 csq per row.
__global__ void prep_convert(const float* __restrict__ c,
                             unsigned char* __restrict__ cq, float* __restrict__ csqg) {
  size_t i = ((size_t)blockIdx.x * blockDim.x + threadIdx.x) * 16;
  if (i >= (size_t)K_CENT * DIM) return;
  floatx4 a0 = *(const floatx4*)(c + i);
  floatx4 a1 = *(const floatx4*)(c + i + 4);
  floatx4 a2 = *(const floatx4*)(c + i + 8);
  floatx4 a3 = *(const floatx4*)(c + i + 12);
  intx4 q = { pk4(a0[0],a0[1],a0[2],a0[3]), pk4(a1[0],a1[1],a1[2],a1[3]),
              pk4(a2[0],a2[1],a2[2],a2[3]), pk4(a3[0],a3[1],a3[2],a3[3]) };
  *(intx4*)(cq + i) = q;
  float s = 0.f;
#pragma unroll
  for (int e = 0; e < 4; ++e)
    s += a0[e]*a0[e] + a1[e]*a1[e] + a2[e]*a2[e] + a3[e]*a3[e];
#pragma unroll
  for (int o = 1; o < 32; o <<= 1) s += __shfl_xor(s, o, 64);
  if ((threadIdx.x & 31) == 0) csqg[i >> 9] = s;
}

// R5 = R4 structure (barrier-free wave-private K-loop) + LOSSLESS compaction.
// 4 waves; wave w privately owns x-rows rowBlock + w*64..+63 (xfA/xfB in
// registers) and stages its OWN 4KB copy of each 64-center x 64B tile chunk
// into a wave-private ring (4 bufs x 4KB, depth 3, 4 glds/step, vmcnt(12)).
// All staging hazards are intra-wave:
//  - read step j: its 4 glds (issued at j-3) retired by vmcnt(12) at j.
//  - write step j targets buf (j+3)%4 = (j-1)%4, whose ds_reads completed
//    at step j-1 (lgkmcnt(0) before that step's MFMAs, program order).
// Each A-frag (2 ds_read_b128) feeds 2 MFMAs (xfA,xfB) -> 1KB LDS/MFMA.
// Rows wave-private => sminU/pool/compaction wave-local, zero block barriers
// in the loop. launch_bounds(256,1) -> 512-VGPR cap, no spill (R2 lesson).
// COMPACTION IS LOSSLESS: per-lane buffer 16 = WCAP/64 >= max entries a lane
// can scan (R3/R4 FAILED from cap-4 dropping survivors => wrong argmin).
// LDS all static (116KB < 160KB gfx950): no dynamic-smem launch ambiguity.
__global__ __launch_bounds__(THREADS, 1)
void kmeans_argmin_pipe(const float* __restrict__ x, const float* __restrict__ cent,
                        const unsigned char* __restrict__ cq,
                        const float* __restrict__ csqg, int* __restrict__ out) {
  __shared__ __align__(16) unsigned char ringLds[4][16384];  // 64 KB rings
  __shared__ __align__(16) float csqL[K_CENT];  // 16 KB
  __shared__ unsigned sminU[TILE_M];            // 1 KB
  __shared__ unsigned long long best[TILE_M];   // 2 KB
  __shared__ unsigned poolK[4][WCAP];           // 16 KB
  __shared__ float    poolS[4][WCAP];           // 16 KB
  __shared__ int candCnt[4];

  const int t = threadIdx.x;
  const int lane = t & 63;
  const int wave = t >> 6;        // 0..3
  const int l31 = lane & 31;
  const int half = lane >> 5;
  const int rowBlock = blockIdx.x * TILE_M;

  sminU[t] = 0xFFFFFFFFu;
  best[t] = ~0ull;
  if (t < 4) candCnt[t] = 0;
#pragma unroll
  for (int i = 0; i < K_CENT / THREADS; ++i) csqL[t + i * THREADS] = csqg[t + i * THREADS];

  // per-lane source offsets for the 4 staging glds (slot s = i*64+lane):
  // slot -> center-row (s>>7)*32+((s>>2)&31), stored pos s&3 holds source
  // chunk (s&3)^(((s>>2)&31)>>1 & 3)  [same swizzle as verified R2 kernel]
  int offI0, offI1, offI2, offI3;
#pragma unroll
  for (int i = 0; i < 4; ++i) {
    int s = i * 64 + lane;
    int rS = (s >> 2) & 31;
    int row = (s >> 7) * 32 + rS;
    int cp = (s & 3) ^ ((rS >> 1) & 3);
    int v = row * DIM + cp * 16;
    if (i == 0) offI0 = v; else if (i == 1) offI1 = v;
    else if (i == 2) offI2 = v; else offI3 = v;
  }

  // fragment read byte offsets within a 4KB buf (rows 32..63 at +2048)
  const int qk = half * 2;
  const int slotLo = 4 * l31 + (qk ^ ((l31 >> 1) & 3));
  const int loB = slotLo * 16;
  const int hiB = (slotLo ^ 1) * 16;
  unsigned char* ringW = ringLds[wave];

  // ---- x -> fp8 fragments in registers: 2 row-halves (64 rows/wave).
  // B-operand: col = lane&31 (x-row), lane>>5 = k-half (bytes half*32..+31)
  intx8 xfA[KSTEPS], xfB[KSTEPS];
  {
    const float* xr = x + (size_t)(rowBlock + wave * 64 + l31) * DIM + half * 32;
#pragma unroll
    for (int ks = 0; ks < KSTEPS; ++ks) {
      int q[8];
#pragma unroll
      for (int j = 0; j < 8; ++j) {
        floatx4 f = *(const floatx4*)(xr + ks * 64 + j * 4);
        q[j] = pk4(f[0], f[1], f[2], f[3]);
      }
      xfA[ks] = (intx8){q[0], q[1], q[2], q[3], q[4], q[5], q[6], q[7]};
    }
    xr += (size_t)32 * DIM;
#pragma unroll
    for (int ks = 0; ks < KSTEPS; ++ks) {
      int q[8];
#pragma unroll
      for (int j = 0; j < 8; ++j) {
        floatx4 f = *(const floatx4*)(xr + ks * 64 + j * 4);
        q[j] = pk4(f[0], f[1], f[2], f[3]);
      }
      xfB[ks] = (intx8){q[0], q[1], q[2], q[3], q[4], q[5], q[6], q[7]};
    }
  }

  __syncthreads();   // init visible; drains ALL vmem -> loop vmcnt count exact

  // prologue: stage steps 0..2 into bufs 0..2 (12 glds outstanding)
#pragma unroll
  for (int s = 0; s < 3; ++s) {
    unsigned char* wb = ringW + (s << 12);
    gload_lds16(cq + s * 64 + offI0, wb);
    gload_lds16(cq + s * 64 + offI1, wb + 1024);
    gload_lds16(cq + s * 64 + offI2, wb + 2048);
    gload_lds16(cq + s * 64 + offI3, wb + 3072);
  }
  unsigned sOff = 3 * 64;   // next prefetch target = step 3

  for (int ct = 0; ct < NCT; ++ct) {
    floatx16 acc00, acc01, acc10, acc11;   // [rowhalf][centergroup]
#pragma unroll
    for (int e = 0; e < 16; ++e) { acc00[e] = 0.f; acc01[e] = 0.f; acc10[e] = 0.f; acc11[e] = 0.f; }

#pragma unroll
    for (int p = 0; p < KSTEPS; ++p) {
      // prefetch step j+3 into buf (p+3)&3 (tail wraps harmlessly in ws)
      {
        unsigned char* wb = ringW + (((p + 3) & 3) << 12);
        gload_lds16(cq + sOff + offI0, wb);
        gload_lds16(cq + sOff + offI1, wb + 1024);
        gload_lds16(cq + sOff + offI2, wb + 2048);
        gload_lds16(cq + sOff + offI3, wb + 3072);
      }
      sOff += (p == 4) ? 32320u : 64u;   // target ks 7->0: jump to next tile
      asm volatile("s_waitcnt vmcnt(12)" ::: "memory");   // step j's 4 landed
      __builtin_amdgcn_sched_barrier(0);

      const unsigned char* rb = ringW + ((p & 3) << 12);
      intx4 lo0 = *(const intx4*)(rb + loB);
      intx4 hi0 = *(const intx4*)(rb + hiB);
      intx4 lo1 = *(const intx4*)(rb + 2048 + loB);
      intx4 hi1 = *(const intx4*)(rb + 2048 + hiB);
      asm volatile("s_waitcnt lgkmcnt(0)" ::: "memory");
      __builtin_amdgcn_sched_barrier(0);
      intx8 b0 = (intx8){lo0[0],lo0[1],lo0[2],lo0[3], hi0[0],hi0[1],hi0[2],hi0[3]};
      intx8 b1 = (intx8){lo1[0],lo1[1],lo1[2],lo1[3], hi1[0],hi1[1],hi1[2],hi1[3]};
      // A = centers (rows), B = x (cols); each A-frag reused for both row-halves
      acc00 = __builtin_amdgcn_mfma_scale_f32_32x32x64_f8f6f4(
          b0, xfA[p], acc00, 0, 0, 0, SCALE1, 0, SCALE1);
      acc01 = __builtin_amdgcn_mfma_scale_f32_32x32x64_f8f6f4(
          b1, xfA[p], acc01, 0, 0, 0, SCALE1, 0, SCALE1);
      acc10 = __builtin_amdgcn_mfma_scale_f32_32x32x64_f8f6f4(
          b0, xfB[p], acc10, 0, 0, 0, SCALE1, 0, SCALE1);
      acc11 = __builtin_amdgcn_mfma_scale_f32_32x32x64_f8f6f4(
          b1, xfB[p], acc11, 0, 0, 0, SCALE1, 0, SCALE1);
    }

    // ---- wave-local epilogue: s(center k) = csq[k] - 2*cross
    // C/D: col = lane&31 (x-row), reg r -> center (r&3)+8*(r>>2)+4*half
    const int ctB = ct << 6;
#pragma unroll
    for (int h = 0; h < 2; ++h) {
      const floatx16& a0 = h ? acc10 : acc00;
      const floatx16& a1 = h ? acc11 : acc01;
      const int srow = wave * 64 + h * 32 + l31;
      float mn = 3.4e38f;
#pragma unroll
      for (int gg = 0; gg < 4; ++gg) {
        floatx4 c0 = *(const floatx4*)&csqL[ctB + 8 * gg + 4 * half];
        floatx4 c1 = *(const floatx4*)&csqL[ctB + 32 + 8 * gg + 4 * half];
#pragma unroll
        for (int e = 0; e < 4; ++e) {
          mn = fminf(mn, c0[e] - 2.f * a0[4 * gg + e]);
          mn = fminf(mn, c1[e] - 2.f * a1[4 * gg + e]);
        }
      }
      mn = fminf(mn, __shfl_xor(mn, 32, 64));   // merge the two center-halves
      if (half == 0) atomicMin(&sminU[srow], mapF(mn));
      WAVE_LDS_FENCE();   // intra-wave: atomic retired before threshold read

      const float thr = unmapF(sminU[srow]) + MARGIN;
#pragma unroll
      for (int gg = 0; gg < 4; ++gg) {
        floatx4 c0 = *(const floatx4*)&csqL[ctB + 8 * gg + 4 * half];
        floatx4 c1 = *(const floatx4*)&csqL[ctB + 32 + 8 * gg + 4 * half];
#pragma unroll
        for (int e = 0; e < 4; ++e) {
          float s0 = c0[e] - 2.f * a0[4 * gg + e];
          if (s0 <= thr) {
            int k = ctB + 8 * gg + 4 * half + e;
            int idx = atomicAdd(&candCnt[wave], 1);
            if (idx < WCAP) { poolK[wave][idx] = ((unsigned)k << 8) | (unsigned)srow; poolS[wave][idx] = s0; }
          }
          float s1 = c1[e] - 2.f * a1[4 * gg + e];
          if (s1 <= thr) {
            int k = ctB + 32 + 8 * gg + 4 * half + e;
            int idx = atomicAdd(&candCnt[wave], 1);
            if (idx < WCAP) { poolK[wave][idx] = ((unsigned)k << 8) | (unsigned)srow; poolS[wave][idx] = s1; }
          }
        }
      }
    }
    WAVE_LDS_FENCE();

    // wave-local LOSSLESS compaction backstop (wave-uniform branch):
    // lane scans i = lane, lane+64, ... < cc <= WCAP=1024 -> <= 16 entries,
    // local buffer holds all 16 -> no survivor can be dropped (R3/R4 bug).
    if (candCnt[wave] > WTRIG) {
      int cc = candCnt[wave]; if (cc > WCAP) cc = WCAP;
      unsigned myK[16]; float myS[16]; int myN = 0;
      for (int i = lane; i < cc; i += 64) {
        int rl = poolK[wave][i] & 255;
        if (poolS[wave][i] <= unmapF(sminU[rl]) + MARGIN) {
          myK[myN] = poolK[wave][i]; myS[myN] = poolS[wave][i]; ++myN;
        }
      }
      WAVE_LDS_FENCE();                 // survivors in regs before overwrite
      if (lane == 0) candCnt[wave] = 0;
      WAVE_LDS_FENCE();
      int base = atomicAdd(&candCnt[wave], myN);
      for (int j = 0; j < myN; ++j) { poolK[wave][base + j] = myK[j]; poolS[wave][base + j] = myS[j]; }
      WAVE_LDS_FENCE();
    }
  }

  __syncthreads();   // drain everything (incl. tail prefetches); pools final

  // ---- fp64-exact refinement of surviving candidates (original fp32 inputs)
  const int grp = t >> 4;   // 16 groups of 16 lanes
  const int sl = t & 15;
  for (int w = 0; w < 4; ++w) {
    int cw = candCnt[w]; if (cw > WCAP) cw = WCAP;
    for (int ci = grp; ci < cw; ci += 16) {
      unsigned cd = poolK[w][ci];
      int rl = cd & 255;
      if (poolS[w][ci] > unmapF(sminU[rl]) + MARGIN) continue;  // group-uniform
      int k = cd >> 8;
      const float* xr = x + (size_t)(rowBlock + rl) * DIM;
      const float* cr = cent + (size_t)k * DIM;
      double d = 0.0;
#pragma unroll
      for (int jj = 0; jj < DIM / 64; ++jj) {
        floatx4 xv = *(const floatx4*)(xr + jj * 64 + sl * 4);
        floatx4 cv = *(const floatx4*)(cr + jj * 64 + sl * 4);
#pragma unroll
        for (int e = 0; e < 4; ++e) {
          double df = (double)xv[e] - (double)cv[e];
          d += df * df;
        }
      }
#pragma unroll
      for (int off = 1; off < 16; off <<= 1) d += __shfl_xor(d, off, 64);
      if (sl == 0) {
        // positive doubles order as uint64; low 12 bits -> index (ties: lower k)
        unsigned long long key =
            ((unsigned long long)__double_as_longlong(d) & ~0xFFFull) | (unsigned long long)k;
        atomicMin(&best[rl], key);
      }
    }
  }
  __syncthreads();
  out[rowBlock + t] = (int)(best[t] & 0xFFFull);
}

// Fallback (no workspace): self-contained 512-thread kernel (known-good).
#define FB_TILE_M 128
#define FB_NKT    32
#define FB_CAP    1536
#define FB_TRIG   1024
__global__ __launch_bounds__(512, 4)
void kmeans_argmin_fb(const float* __restrict__ x, const float* __restrict__ cent,
                      int* __restrict__ out) {
  __shared__ unsigned char ldsA[FB_TILE_M * 64];
  __shared__ unsigned char ldsB[128 * 64];
  __shared__ float csq4[128][4];
  __shared__ unsigned sminU[FB_TILE_M];
  __shared__ unsigned long long best[FB_TILE_M];
  __shared__ unsigned candKey[FB_CAP];
  __shared__ float candS[FB_CAP];
  __shared__ int candCount;

  const int t = threadIdx.x;
  const int lane = t & 63;
  const int wave = t >> 6;
  const int wm = wave >> 1;
  const int wn = wave & 1;
  const int l31 = lane & 31;
  const int half = lane >> 5;
  const int rowBlock = blockIdx.x * FB_TILE_M;

  if (t < FB_TILE_M) { sminU[t] = 0xFFFFFFFFu; best[t] = ~0ull; }
  if (t == 0) candCount = 0;

  const int rS = (t >> 2) & 31;
  const int rowS = (t >> 7) * 32 + rS;
  const int offS = (((t & 3) ^ ((rS >> 1) & 3)) << 4);
  const int qk = half * 2;
  const int fragSlotBase = 4 * l31 + (qk ^ ((l31 >> 1) & 3));

  for (int kt = 0; kt < FB_NKT; ++kt) {
    const int ktBase = kt * 128;
    ((float*)csq4)[t] = 0.f;
    floatx16 acc[2];
#pragma unroll
    for (int fn = 0; fn < 2; ++fn)
#pragma unroll
      for (int e = 0; e < 16; ++e) acc[fn][e] = 0.f;

    for (int ks = 0; ks < KSTEPS; ++ks) {
      const int kd = ks * 64;
      {
        const float* gA = x + (size_t)(rowBlock + rowS) * DIM + kd + offS;
        floatx4 f0 = *(const floatx4*)gA, f1 = *(const floatx4*)(gA + 4);
        floatx4 f2 = *(const floatx4*)(gA + 8), f3 = *(const floatx4*)(gA + 12);
        intx4 q = { pk4(f0[0],f0[1],f0[2],f0[3]), pk4(f1[0],f1[1],f1[2],f1[3]),
                    pk4(f2[0],f2[1],f2[2],f2[3]), pk4(f3[0],f3[1],f3[2],f3[3]) };
        *(intx4*)(ldsA + (size_t)t * 16) = q;
      }
      {
        const float* gB = cent + (size_t)(ktBase + rowS) * DIM + kd + offS;
        floatx4 f0 = *(const floatx4*)gB, f1 = *(const floatx4*)(gB + 4);
        floatx4 f2 = *(const floatx4*)(gB + 8), f3 = *(const floatx4*)(gB + 12);
        intx4 q = { pk4(f0[0],f0[1],f0[2],f0[3]), pk4(f1[0],f1[1],f1[2],f1[3]),
                    pk4(f2[0],f2[1],f2[2],f2[3]), pk4(f3[0],f3[1],f3[2],f3[3]) };
        *(intx4*)(ldsB + (size_t)t * 16) = q;
        float s = 0.f;
#pragma unroll
        for (int e = 0; e < 4; ++e)
          s += f0[e]*f0[e] + f1[e]*f1[e] + f2[e]*f2[e] + f3[e]*f3[e];
        csq4[rowS][t & 3] += s;
      }
      __syncthreads();

      intx8 aF, bF[2];
      {
        int s0 = wm * 128 + fragSlotBase;
        intx4 lo = *(const intx4*)(ldsA + s0 * 16);
        intx4 hi = *(const intx4*)(ldsA + (s0 ^ 1) * 16);
        aF = (intx8){lo[0], lo[1], lo[2], lo[3], hi[0], hi[1], hi[2], hi[3]};
      }
#pragma unroll
      for (int fn = 0; fn < 2; ++fn) {
        int s0 = (wn * 2 + fn) * 128 + fragSlotBase;
        intx4 lo = *(const intx4*)(ldsB + s0 * 16);
        intx4 hi = *(const intx4*)(ldsB + (s0 ^ 1) * 16);
        bF[fn] = (intx8){lo[0], lo[1], lo[2], lo[3], hi[0], hi[1], hi[2], hi[3]};
      }
#pragma unroll
      for (int fn = 0; fn < 2; ++fn)
        acc[fn] = __builtin_amdgcn_mfma_scale_f32_32x32x64_f8f6f4(
            aF, bF[fn], acc[fn], 0, 0, 0, SCALE1, 0, SCALE1);
      __syncthreads();
    }

    float cs[2];
#pragma unroll
    for (int fn = 0; fn < 2; ++fn) {
      int cl = wn * 64 + fn * 32 + l31;
      cs[fn] = csq4[cl][0] + csq4[cl][1] + csq4[cl][2] + csq4[cl][3];
    }

#pragma unroll
    for (int r = 0; r < 16; ++r) {
      float v = fminf(cs[0] - 2.f * acc[0][r], cs[1] - 2.f * acc[1][r]);
      v = fminf(v, __shfl_xor(v, 1, 64));
      v = fminf(v, __shfl_xor(v, 2, 64));
      v = fminf(v, __shfl_xor(v, 4, 64));
      v = fminf(v, __shfl_xor(v, 8, 64));
      v = fminf(v, __shfl_xor(v, 16, 64));
      if (l31 == 0) {
        int srow = wm * 32 + (r & 3) + 8 * (r >> 2) + 4 * half;
        atomicMin(&sminU[srow], mapF(v));
      }
    }
    __syncthreads();

#pragma unroll
    for (int r = 0; r < 16; ++r) {
      int srow = wm * 32 + (r & 3) + 8 * (r >> 2) + 4 * half;
      float thr = unmapF(sminU[srow]) + MARGIN;
#pragma unroll
      for (int fn = 0; fn < 2; ++fn) {
        float s = cs[fn] - 2.f * acc[fn][r];
        if (s <= thr) {
          int k = ktBase + wn * 64 + fn * 32 + l31;
          int idx = atomicAdd(&candCount, 1);
          if (idx < FB_CAP) {
            candKey[idx] = ((unsigned)k << 7) | (unsigned)srow;
            candS[idx] = s;
          }
        }
      }
    }
    __syncthreads();

    if (candCount > FB_TRIG) {
      int cc = candCount; if (cc > FB_CAP) cc = FB_CAP;
      unsigned myK[4]; float myS[4]; int myN = 0;
      for (int i = t; i < cc; i += 512) {
        int rl = candKey[i] & 127;
        if (candS[i] <= unmapF(sminU[rl]) + MARGIN && myN < 4) {
          myK[myN] = candKey[i]; myS[myN] = candS[i]; ++myN;
        }
      }
      __syncthreads();
      if (t == 0) candCount = 0;
      __syncthreads();
      int base = atomicAdd(&candCount, myN);
      for (int j = 0; j < myN; ++j) { candKey[base + j] = myK[j]; candS[base + j] = myS[j]; }
      __syncthreads();
    }
  }

  int cnt = candCount; if (cnt > FB_CAP) cnt = FB_CAP;
  const int g = t >> 4;
  const int sl = t & 15;
  for (int ci = g; ci < cnt; ci += 32) {
    unsigned cd = candKey[ci];
    int rl = cd & 127;
    if (candS[ci] > unmapF(sminU[rl]) + MARGIN) continue;
    int k = cd >> 7;
    const float* xr = x + (size_t)(rowBlock + rl) * DIM;
    const float* cr = cent + (size_t)k * DIM;
    double d = 0.0;
#pragma unroll
    for (int j = 0; j < DIM / 64; ++j) {
      floatx4 xv = *(const floatx4*)(xr + j * 64 + sl * 4);
      floatx4 cv = *(const floatx4*)(cr + j * 64 + sl * 4);
#pragma unroll
      for (int e = 0; e < 4; ++e) {
        double df = (double)xv[e] - (double)cv[e];
        d += df * df;
      }
    }
#pragma unroll
    for (int off = 1; off < 16; off <<= 1) d += __shfl_xor(d, off, 64);
    if (sl == 0) {
      unsigned long long key =
          ((unsigned long long)__double_as_longlong(d) & ~0xFFFull) | (unsigned long long)k;
      atomicMin(&best[rl], key);
    }
  }
  __syncthreads();
  if (t < FB_TILE_M) out[rowBlock + t] = (int)(best[t] & 0xFFFull);
}

extern "C" void kernel_launch(void* const* d_in, const int* in_sizes, int n_in,
                              void* d_out, int out_size, void* d_ws, size_t ws_size,
                              hipStream_t stream) {
  const float* x = (const float*)d_in[0];
  const float* cent = (const float*)d_in[1];
  int* out = (int*)d_out;
  const size_t nXq = (size_t)N_ROWS * DIM;          // ws-size gate (known-good)
  const size_t nCq = (size_t)K_CENT * DIM;          // 2 MiB fp8
  const size_t nCsq = (size_t)K_CENT * sizeof(float);

  if (ws_size >= nXq + nCq + nCsq) {
    unsigned char* cq = (unsigned char*)d_ws;
    float* csqg = (float*)(cq + nCq);
    const size_t total16 = nCq / 16;
    prep_convert<<<(unsigned)((total16 + 255) / 256), 256, 0, stream>>>(cent, cq, csqg);
    kmeans_argmin_pipe<<<N_ROWS / TILE_M, THREADS, 0, stream>>>(x, cent, cq, csqg, out);
  } else {
    kmeans_argmin_fb<<<N_ROWS / FB_TILE_M, 512, 0, stream>>>(x, cent, out);
  }
}